// Round 9
// baseline (902.853 us; speedup 1.0000x reference)
//
#include <hip/hip_runtime.h>
#include <hip/hip_bf16.h>

#define VOCAB 50000
#define EMBD  512
#define HID   1024
#define NB    256
#define SEQW  26
#define MTOT  (SEQW * NB)   /* 6656 */
#define NGATE (4 * HID)     /* 4096 */

typedef short short8 __attribute__((ext_vector_type(8)));
typedef _Float16 half8 __attribute__((ext_vector_type(8)));
typedef float f32x4  __attribute__((ext_vector_type(4)));
typedef float f32x16 __attribute__((ext_vector_type(16)));

__device__ __forceinline__ unsigned short f16bits(_Float16 h) {
    union { _Float16 h; unsigned short u; } cv; cv.h = h; return cv.u;
}

// ---------------- init: zero h slot0 + barrier state ----------------
__global__ void init_kernel(unsigned short* __restrict__ hBuf,
                            unsigned int* __restrict__ bar) {
    int idx = blockIdx.x * blockDim.x + threadIdx.x;  // 1024 x 256
    hBuf[idx] = 0;                                     // slot 0 = h_0 = 0
    if (idx < 4096) bar[idx] = 0;
}

// ---------------- embedding: thread-per-element gather + tanh -> fp16 -------
__global__ void embed_kernel(const int* __restrict__ qv,
                             const float* __restrict__ Wemb,
                             unsigned short* __restrict__ eHi) {
    int gid = blockIdx.x * 256 + threadIdx.x;  // over MTOT*EMBD
    int pair = gid >> 9;                       // t*NB + b
    int e = gid & 511;
    int t = pair >> 8, b = pair & 255;
    int tok = qv[b * SEQW + t];
    unsigned short hi = 0;
    if (tok > 0) {
        float x = Wemb[(size_t)e * VOCAB + (tok - 1)];
        hi = f16bits((_Float16)tanhf(x));
    }
    eHi[gid] = hi;
}

// ---------------- weight conversion: ih fp16, hh fp16, bsum -----------------
__global__ void convw_kernel(const float* __restrict__ Wih,
                             const float* __restrict__ Whh,
                             const float* __restrict__ b_ih,
                             const float* __restrict__ b_hh,
                             unsigned short* __restrict__ ih,
                             unsigned short* __restrict__ hh,
                             float* __restrict__ bsum) {
    int j = blockIdx.x; // 0..4095
    if (threadIdx.x == 0) bsum[j] = b_ih[j] + b_hh[j];
    for (int col = threadIdx.x; col < EMBD; col += blockDim.x)
        ih[(size_t)j * EMBD + col] = f16bits((_Float16)Wih[(size_t)j * EMBD + col]);
    for (int col = threadIdx.x; col < HID; col += blockDim.x)
        hh[(size_t)j * HID + col] = f16bits((_Float16)Whh[(size_t)j * HID + col]);
}

// ---------------- pre-GEMM: G0n = emb @ Wih^T + bias (1-term fp16) ----------
// G0n layout: [t][ct 0..63][b 0..255][cidx 0..63], cidx = gate*16 + (jh&15).
__global__ __launch_bounds__(512, 2) void pregemm_kernel(
    const unsigned short* __restrict__ eHi,
    const unsigned short* __restrict__ ih,
    const float* __restrict__ bsum,
    float* __restrict__ G0n)
{
    int id = blockIdx.x;
    int xcd = id & 7;
    int lid = id >> 3;
    int pc = xcd * 4 + (lid & 3);   // 0..31 col tile (32 jh x 4 gates)
    int pm = lid >> 2;              // 0..51 row tile (128 rows)
    int jh0 = pc * 32;
    int m0  = pm * 128;

    int wave = threadIdx.x >> 6;
    int g  = wave & 3;
    int mh = wave >> 2;
    int lane = threadIdx.x & 63;
    int col16 = lane & 15;
    int g4 = lane >> 4;

    f32x4 acc[4][2];
    #pragma unroll
    for (int fm = 0; fm < 4; ++fm)
        #pragma unroll
        for (int fn = 0; fn < 2; ++fn)
            acc[fm][fn] = (f32x4){0.f, 0.f, 0.f, 0.f};

    const unsigned short* aP[4];
    #pragma unroll
    for (int fm = 0; fm < 4; ++fm)
        aP[fm] = eHi + (size_t)(m0 + mh * 64 + fm * 16 + col16) * EMBD + 8 * g4;
    const unsigned short* bP[2];
    #pragma unroll
    for (int fn = 0; fn < 2; ++fn)
        bP[fn] = ih + (size_t)(g * HID + jh0 + fn * 16 + col16) * EMBD + 8 * g4;

    half8 rA[2][4], rB[2][2];
    #pragma unroll
    for (int fm = 0; fm < 4; ++fm) rA[0][fm] = *(const half8*)(const void*)(aP[fm]);
    #pragma unroll
    for (int fn = 0; fn < 2; ++fn) rB[0][fn] = *(const half8*)(const void*)(bP[fn]);

    #pragma unroll
    for (int kc = 0; kc < 16; ++kc) {
        const int cur = kc & 1, nxt = cur ^ 1;
        if (kc < 15) {
            int off = (kc + 1) * 32;
            #pragma unroll
            for (int fm = 0; fm < 4; ++fm)
                rA[nxt][fm] = *(const half8*)(const void*)(aP[fm] + off);
            #pragma unroll
            for (int fn = 0; fn < 2; ++fn)
                rB[nxt][fn] = *(const half8*)(const void*)(bP[fn] + off);
        }
        #pragma unroll
        for (int fm = 0; fm < 4; ++fm)
            #pragma unroll
            for (int fn = 0; fn < 2; ++fn)
                acc[fm][fn] = __builtin_amdgcn_mfma_f32_16x16x32_f16(
                    rA[cur][fm], rB[cur][fn], acc[fm][fn], 0, 0, 0);
    }

    float bv[2];
    #pragma unroll
    for (int fn = 0; fn < 2; ++fn)
        bv[fn] = bsum[g * HID + jh0 + fn * 16 + col16];

    #pragma unroll
    for (int fm = 0; fm < 4; ++fm)
        #pragma unroll
        for (int fn = 0; fn < 2; ++fn)
            #pragma unroll
            for (int r = 0; r < 4; ++r) {
                int row = m0 + mh * 64 + fm * 16 + g4 * 4 + r;
                int t = row >> 8, b = row & 255;
                int jhc = jh0 + fn * 16 + col16;          // 0..1023
                int ct = jhc >> 4, jl = jhc & 15;
                G0n[(((size_t)t * 64 + ct) * 256 + b) * 64 + g * 16 + jl] =
                    acc[fm][fn][r] + bv[fn];
            }
}

// ---------------- persistent LSTM: fp16 32x32 MFMA, K-split waves -----------
// 256 blocks x 1024 threads (16 waves, 4/SIMD), 1 block/CU.
// Group = 64 blocks (grp=(bx&7)>>1): batch rows [grp*64,+64) x all 4096
// gate-cols; independent recurrence + own hierarchical barrier.
// Wave wv: mh=wv&1 (32-row M-frag), kq=(wv>>1)&3 (K=256 slice), nh=wv>>3
// (32-col N-frag). Each wave: 16x mfma_32x32x16_f16, A loaded once (no gate
// duplication). K-partials reduced in LDS: kq0 writes, kq1-3 ds_add_f32.
// h exchange: sc1 relaxed agent stores (write-through to L3); readers
// first-touch-miss; ct-pairing keeps each 64B h-line written by one XCD.
__global__ __launch_bounds__(1024, 4) void lstm_persist(
    const unsigned short* __restrict__ hh,     // fp16 Whh [4096][1024]
    unsigned short* __restrict__ hBuf,         // 27 slots of NB*HID fp16
    const float* __restrict__ G0n,
    float* __restrict__ out,
    unsigned int* __restrict__ bar)
{
    extern __shared__ char smem[];
    // [0,131072): Whh slice fp16, 64 rows x 2048B, XOR-swizzled
    // [131072,147456): gbuf[64][64] floats
    float* gbuf = (float*)(smem + 131072);

    int bx = blockIdx.x;
    int grp = (bx & 7) >> 1;                     // 0..3
    int ct  = ((bx >> 3) & 31) + 32 * (bx & 1);  // 0..63
    int m0  = grp * 64;
    int jh0 = ct * 16;

    int tid = threadIdx.x;
    int wv = tid >> 6;
    int mh = wv & 1, kq = (wv >> 1) & 3, nh = wv >> 3;
    int lane = tid & 63;
    int l31 = lane & 31, l5 = lane >> 5;

    // ---- stage Whh gate-rows into LDS (once), XOR-swizzled ----
    // lds row r = gate*16 + jl  <->  Whh row gate*HID + jh0 + jl
    const char* hhB = (const char*)hh;
    for (int i = tid; i < 8192; i += 1024) {
        int r = i >> 7;
        int byteInRow = (i & 127) << 4;
        size_t grow = (size_t)((r >> 4) * HID + jh0 + (r & 15)) * HID * 2;
        int dst = r * 2048 + (byteInRow ^ ((r & 7) << 4));
        *(short8*)(smem + dst) = *(const short8*)(hhB + grow + byteInRow);
    }

    // epilogue: 1 cell/thread: (ml = tid>>4, jl = tid&15)
    int ml = tid >> 4, jl = tid & 15;

    // ---- G0 prefetch for t=0 ----
    float g0v[4];
    {
        const float* p = G0n + (((size_t)ct) * 256 + (m0 + ml)) * 64 + jl;
        #pragma unroll
        for (int q = 0; q < 4; ++q) g0v[q] = p[q * 16];
    }

    float cReg = 0.f;
    __syncthreads();

    // B-read addressing (constant per thread)
    int cB = nh * 32 + l31;                 // gate-col index 0..63
    int bRowBase = cB * 2048;
    int bXor = (cB & 7) << 4;
    int bInner0 = kq * 512 + l5 * 16;

    // barrier pointers
    unsigned int* subC = bar + grp * 256 + (ct >> 3) * 16;
    unsigned int* rootC = bar + 1024 + grp * 16;
    unsigned int* gen = bar + 1088 + grp * 16;

    for (int t = 0; t < SEQW; ++t) {
        const unsigned short* hIn = hBuf + (size_t)t * NB * HID;
        unsigned short* hOut = hBuf + (size_t)(t + 1) * NB * HID;

        const char* aB = (const char*)hIn +
            ((size_t)(m0 + mh * 32 + l31) * HID + kq * 256 + l5 * 8) * 2;

        f32x16 acc = {};

        // ---- K loop: 16 kk, A loads batched 8+8 ----
        #pragma unroll
        for (int hf = 0; hf < 2; ++hf) {
            half8 aR[8];
            #pragma unroll
            for (int j = 0; j < 8; ++j)
                aR[j] = *(const half8*)(const void*)(aB + (hf * 8 + j) * 32);
            #pragma unroll
            for (int j = 0; j < 8; ++j) {
                int kk = hf * 8 + j;
                half8 bF = *(const half8*)(const void*)(
                    smem + bRowBase + ((bInner0 + kk * 32) ^ bXor));
                acc = __builtin_amdgcn_mfma_f32_32x32x16_f16(aR[j], bF, acc, 0, 0, 0);
            }
        }

        // ---- reduce K-partials in LDS ----
        __syncthreads();                 // prev epilogue reads done (barrier ago)
        if (kq == 0) {
            #pragma unroll
            for (int r = 0; r < 16; ++r) {
                int row = mh * 32 + (r & 3) + 8 * (r >> 2) + 4 * l5;
                gbuf[row * 64 + cB] = acc[r];
            }
        }
        __syncthreads();
        if (kq != 0) {
            #pragma unroll
            for (int r = 0; r < 16; ++r) {
                int row = mh * 32 + (r & 3) + 8 * (r >> 2) + 4 * l5;
                atomicAdd(&gbuf[row * 64 + cB], acc[r]);
            }
        }
        __syncthreads();

        // ---- epilogue: 1 cell/thread, c in register ----
        float gi  = gbuf[ml * 64 + jl]      + g0v[0];
        float gf  = gbuf[ml * 64 + 16 + jl] + g0v[1];
        float gg_ = gbuf[ml * 64 + 32 + jl] + g0v[2];
        float go  = gbuf[ml * 64 + 48 + jl] + g0v[3];
        float si = 1.0f / (1.0f + expf(-gi));
        float sf = 1.0f / (1.0f + expf(-gf));
        float so = 1.0f / (1.0f + expf(-go));
        float tg = tanhf(gg_);
        float cN = sf * cReg + si * tg;
        float hN = so * tanhf(cN);
        cReg = cN;
        size_t p = (size_t)(m0 + ml) * HID + jh0 + jl;

        if (t == SEQW - 1) {
            out[p] = hN;
        } else {
            __hip_atomic_store((unsigned short*)(hOut + p),
                               f16bits((_Float16)hN),
                               __ATOMIC_RELAXED, __HIP_MEMORY_SCOPE_AGENT);

            // prefetch next step's G0 (constant data, no ordering needed)
            const float* pg = G0n +
                (((size_t)(t + 1) * 64 + ct) * 256 + (m0 + ml)) * 64 + jl;
            #pragma unroll
            for (int q = 0; q < 4; ++q) g0v[q] = pg[q * 16];

            // ---- hierarchical group barrier (all relaxed; sc1 data at L3) --
            __syncthreads();             // drains vmcnt: h stores acked
            if (tid == 0) {
                unsigned int t1 = (unsigned int)(t + 1);
                unsigned int so_ = __hip_atomic_fetch_add(
                    subC, 1u, __ATOMIC_RELAXED, __HIP_MEMORY_SCOPE_AGENT);
                if (so_ == t1 * 8u - 1u) {
                    unsigned int ro = __hip_atomic_fetch_add(
                        rootC, 1u, __ATOMIC_RELAXED, __HIP_MEMORY_SCOPE_AGENT);
                    if (ro == t1 * 8u - 1u) {
                        __hip_atomic_store(gen, t1, __ATOMIC_RELAXED,
                                           __HIP_MEMORY_SCOPE_AGENT);
                    }
                }
                while (__hip_atomic_load(gen, __ATOMIC_RELAXED,
                                         __HIP_MEMORY_SCOPE_AGENT) < t1) {
                    __builtin_amdgcn_s_sleep(1);
                }
            }
            __syncthreads();
        }
    }
}

extern "C" void kernel_launch(void* const* d_in, const int* in_sizes, int n_in,
                              void* d_out, int out_size, void* d_ws, size_t ws_size,
                              hipStream_t stream) {
    const int*   qv   = (const int*)d_in[0];
    const float* Wemb = (const float*)d_in[2];
    const float* Wih  = (const float*)d_in[3];
    const float* Whh  = (const float*)d_in[4];
    const float* b_ih = (const float*)d_in[5];
    const float* b_hh = (const float*)d_in[6];
    float* out = (float*)d_out;

    char* ws = (char*)d_ws;
    size_t off = 0;
    unsigned short* eHi  = (unsigned short*)(ws + off); off += (size_t)MTOT * EMBD * 2;
    unsigned short* ih   = (unsigned short*)(ws + off); off += (size_t)NGATE * EMBD * 2;
    unsigned short* hh   = (unsigned short*)(ws + off); off += (size_t)NGATE * HID * 2;
    unsigned short* hBuf = (unsigned short*)(ws + off); off += (size_t)(SEQW + 1) * NB * HID * 2;
    float* bsum          = (float*)(ws + off);          off += (size_t)NGATE * 4;
    unsigned int* bar    = (unsigned int*)(ws + off);   off += 16384;
    off = (off + 255) & ~(size_t)255;
    float* G0n           = (float*)(ws + off);          off += (size_t)MTOT * NGATE * 4; // 109 MB

    init_kernel<<<NB * HID / 256, 256, 0, stream>>>(hBuf, bar);
    embed_kernel<<<MTOT * EMBD / 256, 256, 0, stream>>>(qv, Wemb, eHi);
    convw_kernel<<<NGATE, 256, 0, stream>>>(Wih, Whh, b_ih, b_hh, ih, hh, bsum);
    pregemm_kernel<<<1664, 512, 0, stream>>>(eHi, ih, bsum, G0n);

    lstm_persist<<<256, 1024, 147456, stream>>>(hh, hBuf, G0n, out, bar);
}

// Round 10
// 676.634 us; speedup vs baseline: 1.3343x; 1.3343x over previous
//
#include <hip/hip_runtime.h>
#include <hip/hip_bf16.h>

#define VOCAB 50000
#define EMBD  512
#define HID   1024
#define NB    256
#define SEQW  26
#define MTOT  (SEQW * NB)   /* 6656 */
#define NGATE (4 * HID)     /* 4096 */

typedef short short8 __attribute__((ext_vector_type(8)));
typedef _Float16 half8 __attribute__((ext_vector_type(8)));
typedef float f32x4  __attribute__((ext_vector_type(4)));
typedef float f32x2  __attribute__((ext_vector_type(2)));

__device__ __forceinline__ unsigned short f16bits(_Float16 h) {
    union { _Float16 h; unsigned short u; } cv; cv.h = h; return cv.u;
}

// ---------------- init: zero h slot0 + barrier state ----------------
__global__ void init_kernel(unsigned short* __restrict__ hBuf,
                            unsigned int* __restrict__ bar) {
    int idx = blockIdx.x * blockDim.x + threadIdx.x;  // 1024 x 256
    hBuf[idx] = 0;                                     // slot 0 = h_0 = 0
    if (idx < 4096) bar[idx] = 0;
}

// ---------------- embedding: thread-per-element gather + tanh -> fp16 -------
__global__ void embed_kernel(const int* __restrict__ qv,
                             const float* __restrict__ Wemb,
                             unsigned short* __restrict__ eHi) {
    int gid = blockIdx.x * 256 + threadIdx.x;  // over MTOT*EMBD
    int pair = gid >> 9;                       // t*NB + b
    int e = gid & 511;
    int t = pair >> 8, b = pair & 255;
    int tok = qv[b * SEQW + t];
    unsigned short hi = 0;
    if (tok > 0) {
        float x = Wemb[(size_t)e * VOCAB + (tok - 1)];
        hi = f16bits((_Float16)tanhf(x));
    }
    eHi[gid] = hi;
}

// ---------------- weight conversion: ih fp16, hh fp16, bsum -----------------
__global__ void convw_kernel(const float* __restrict__ Wih,
                             const float* __restrict__ Whh,
                             const float* __restrict__ b_ih,
                             const float* __restrict__ b_hh,
                             unsigned short* __restrict__ ih,
                             unsigned short* __restrict__ hh,
                             float* __restrict__ bsum) {
    int j = blockIdx.x; // 0..4095
    if (threadIdx.x == 0) bsum[j] = b_ih[j] + b_hh[j];
    for (int col = threadIdx.x; col < EMBD; col += blockDim.x)
        ih[(size_t)j * EMBD + col] = f16bits((_Float16)Wih[(size_t)j * EMBD + col]);
    for (int col = threadIdx.x; col < HID; col += blockDim.x)
        hh[(size_t)j * HID + col] = f16bits((_Float16)Whh[(size_t)j * HID + col]);
}

// ---------------- pre-GEMM: G0n = emb @ Wih^T + bias (1-term fp16) ----------
// G0n layout: [t][ct 0..63][b 0..255][cidx 0..63], cidx = gate*16 + (jh&15).
__global__ __launch_bounds__(512, 2) void pregemm_kernel(
    const unsigned short* __restrict__ eHi,
    const unsigned short* __restrict__ ih,
    const float* __restrict__ bsum,
    float* __restrict__ G0n)
{
    int id = blockIdx.x;
    int xcd = id & 7;
    int lid = id >> 3;
    int pc = xcd * 4 + (lid & 3);   // 0..31 col tile (32 jh x 4 gates)
    int pm = lid >> 2;              // 0..51 row tile (128 rows)
    int jh0 = pc * 32;
    int m0  = pm * 128;

    int wave = threadIdx.x >> 6;
    int g  = wave & 3;
    int mh = wave >> 2;
    int lane = threadIdx.x & 63;
    int col16 = lane & 15;
    int g4 = lane >> 4;

    f32x4 acc[4][2];
    #pragma unroll
    for (int fm = 0; fm < 4; ++fm)
        #pragma unroll
        for (int fn = 0; fn < 2; ++fn)
            acc[fm][fn] = (f32x4){0.f, 0.f, 0.f, 0.f};

    const unsigned short* aP[4];
    #pragma unroll
    for (int fm = 0; fm < 4; ++fm)
        aP[fm] = eHi + (size_t)(m0 + mh * 64 + fm * 16 + col16) * EMBD + 8 * g4;
    const unsigned short* bP[2];
    #pragma unroll
    for (int fn = 0; fn < 2; ++fn)
        bP[fn] = ih + (size_t)(g * HID + jh0 + fn * 16 + col16) * EMBD + 8 * g4;

    half8 rA[2][4], rB[2][2];
    #pragma unroll
    for (int fm = 0; fm < 4; ++fm) rA[0][fm] = *(const half8*)(const void*)(aP[fm]);
    #pragma unroll
    for (int fn = 0; fn < 2; ++fn) rB[0][fn] = *(const half8*)(const void*)(bP[fn]);

    #pragma unroll
    for (int kc = 0; kc < 16; ++kc) {
        const int cur = kc & 1, nxt = cur ^ 1;
        if (kc < 15) {
            int off = (kc + 1) * 32;
            #pragma unroll
            for (int fm = 0; fm < 4; ++fm)
                rA[nxt][fm] = *(const half8*)(const void*)(aP[fm] + off);
            #pragma unroll
            for (int fn = 0; fn < 2; ++fn)
                rB[nxt][fn] = *(const half8*)(const void*)(bP[fn] + off);
        }
        #pragma unroll
        for (int fm = 0; fm < 4; ++fm)
            #pragma unroll
            for (int fn = 0; fn < 2; ++fn)
                acc[fm][fn] = __builtin_amdgcn_mfma_f32_16x16x32_f16(
                    rA[cur][fm], rB[cur][fn], acc[fm][fn], 0, 0, 0);
    }

    float bv[2];
    #pragma unroll
    for (int fn = 0; fn < 2; ++fn)
        bv[fn] = bsum[g * HID + jh0 + fn * 16 + col16];

    #pragma unroll
    for (int fm = 0; fm < 4; ++fm)
        #pragma unroll
        for (int fn = 0; fn < 2; ++fn)
            #pragma unroll
            for (int r = 0; r < 4; ++r) {
                int row = m0 + mh * 64 + fm * 16 + g4 * 4 + r;
                int t = row >> 8, b = row & 255;
                int jhc = jh0 + fn * 16 + col16;          // 0..1023
                int ct = jhc >> 4, jl = jhc & 15;
                G0n[(((size_t)t * 64 + ct) * 256 + b) * 64 + g * 16 + jl] =
                    acc[fm][fn][r] + bv[fn];
            }
}

// ---------------- persistent LSTM: fp16 1-term, sc1 h-exchange --------------
// 256 blocks x 512 threads (8 waves, 2/SIMD), 1 block/CU. Group = 64 blocks
// (grp=(bx&7)>>1 -> XCD pair): batch rows [grp*64,+64) x all 4096 gate-cols.
// Wave (gate g, mh): 2 Mfrags x 1 Nfrag, K=1024 in 32 kk steps.
// R10 deltas vs R8: G0 prefetch at loop top (post-barrier, hides under
// K-loop); gbuf [4][64][20] (epilogue 8-way conflict -> ~2-way); packed u32
// h-store; t=0 K-loop skipped (h==0).
__global__ __launch_bounds__(512, 1) void lstm_persist(
    const unsigned short* __restrict__ hh,     // fp16 Whh [4096][1024]
    unsigned short* __restrict__ hBuf,         // 27 slots of NB*HID fp16
    const float* __restrict__ G0n,
    float* __restrict__ out,
    unsigned int* __restrict__ bar)
{
    extern __shared__ char smem[];
    // [0,131072): Whh slice fp16, 64 rows x 2048B, XOR-swizzled
    // [131072, 151552): gbuf[4][64][20] floats
    float* gbuf = (float*)(smem + 131072);

    int bx = blockIdx.x;
    int grp = (bx & 7) >> 1;                     // 0..3
    int ct  = ((bx >> 3) & 31) + 32 * (bx & 1);  // 0..63
    int m0  = grp * 64;
    int jh0 = ct * 16;

    int tid = threadIdx.x;
    int w = tid >> 6;
    int gate = w & 3, mh = w >> 2;
    int lane = tid & 63;
    int col16 = lane & 15, g4 = lane >> 4;

    unsigned int* cnt = bar + grp * 16;
    unsigned int* gen = bar + 1024 + grp * 16;

    // ---- stage Whh gate-rows into LDS (once), XOR-swizzled ----
    const char* hhB = (const char*)hh;
    for (int i = tid; i < 8192; i += 512) {
        int r = i >> 4;
        int byteInRow = (i & 15) << 7;   // 8 chunks of 128B per row half.. no:
        // simpler: i over 64 rows x 128 chunks of 16B
        r = i >> 7;
        byteInRow = (i & 127) << 4;
        size_t grow = (size_t)((r >> 4) * HID + jh0 + (r & 15)) * HID * 2;
        int dst = r * 2048 + (byteInRow ^ ((r & 7) << 4));
        *(short8*)(smem + dst) = *(const short8*)(hhB + grow + byteInRow);
    }

    // epilogue mapping: thread owns (ml = tid>>3, jl2 = 2*(tid&7), +1)
    int ml = tid >> 3, jl2 = (tid & 7) * 2;

    float cReg[2] = {0.f, 0.f};
    __syncthreads();

    int bbase = (gate * 16 + col16) * 2048;
    int bxor = (col16 & 7) << 4;

    for (int t = 0; t < SEQW; ++t) {
        const unsigned short* hIn = hBuf + (size_t)t * NB * HID;
        unsigned short* hOut = hBuf + (size_t)(t + 1) * NB * HID;

        // ---- G0 prefetch for THIS step (post-barrier; hides under K-loop) --
        f32x2 g0v[4];
        {
            const float* pg = G0n +
                (((size_t)t * 64 + ct) * 256 + (m0 + ml)) * 64 + jl2;
            #pragma unroll
            for (int q = 0; q < 4; ++q) g0v[q] = *(const f32x2*)(pg + q * 16);
        }

        f32x4 acc0 = {0.f, 0.f, 0.f, 0.f};
        f32x4 acc1 = {0.f, 0.f, 0.f, 0.f};

        if (t > 0) {
            const unsigned short* r0 = hIn + (size_t)(m0 + mh * 32 + col16) * HID + 8 * g4;
            const unsigned short* r1 = r0 + (size_t)16 * HID;

            // ---- K loop in 2 halves; 32 loads straight-line per half ----
            #pragma unroll
            for (int hf = 0; hf < 2; ++hf) {
                half8 aA[16], aB[16];
                #pragma unroll
                for (int k = 0; k < 16; ++k) {
                    aA[k] = *(const half8*)(const void*)(r0 + (hf * 16 + k) * 32);
                    aB[k] = *(const half8*)(const void*)(r1 + (hf * 16 + k) * 32);
                }
                #pragma unroll
                for (int k = 0; k < 16; ++k) {
                    int kk = hf * 16 + k;
                    int boff = ((kk * 64 + g4 * 16) ^ bxor);
                    half8 bf = *(const half8*)(const void*)(smem + bbase + boff);
                    acc0 = __builtin_amdgcn_mfma_f32_16x16x32_f16(aA[k], bf, acc0, 0, 0, 0);
                    acc1 = __builtin_amdgcn_mfma_f32_16x16x32_f16(aB[k], bf, acc1, 0, 0, 0);
                }
            }
        }

        // scatter: gbuf[gate][row][col16], row stride 20 floats
        #pragma unroll
        for (int r = 0; r < 4; ++r) {
            gbuf[(gate * 64 + mh * 32 + g4 * 4 + r) * 20 + col16] = acc0[r];
            gbuf[(gate * 64 + mh * 32 + 16 + g4 * 4 + r) * 20 + col16] = acc1[r];
        }
        __syncthreads();

        // ---- epilogue: 2 adjacent cells/thread, c in registers ----
        f32x2 gv[4];
        #pragma unroll
        for (int q = 0; q < 4; ++q)
            gv[q] = *(const f32x2*)&gbuf[(q * 64 + ml) * 20 + jl2];

        float hN[2];
        #pragma unroll
        for (int u = 0; u < 2; ++u) {
            float gi  = gv[0][u] + g0v[0][u];
            float gf  = gv[1][u] + g0v[1][u];
            float gg_ = gv[2][u] + g0v[2][u];
            float go  = gv[3][u] + g0v[3][u];
            float si = 1.0f / (1.0f + expf(-gi));
            float sf = 1.0f / (1.0f + expf(-gf));
            float so = 1.0f / (1.0f + expf(-go));
            float tg = tanhf(gg_);
            float cN = sf * cReg[u] + si * tg;
            hN[u] = so * tanhf(cN);
            cReg[u] = cN;
        }
        size_t p = (size_t)(m0 + ml) * HID + jh0 + jl2;
        if (t == SEQW - 1) {
            *(f32x2*)(out + p) = (f32x2){hN[0], hN[1]};
        } else {
            unsigned int hv = (unsigned int)f16bits((_Float16)hN[0]) |
                              ((unsigned int)f16bits((_Float16)hN[1]) << 16);
            __hip_atomic_store((unsigned int*)(hOut + p), hv,
                               __ATOMIC_RELAXED, __HIP_MEMORY_SCOPE_AGENT);

            // ---- group barrier: all-relaxed (sc1 data already at L3) ----
            __syncthreads();   // drains vmcnt: h stores acked at L3
            if (tid == 0) {
                unsigned int t1 = (unsigned int)(t + 1);
                unsigned int old = __hip_atomic_fetch_add(
                    cnt, 1u, __ATOMIC_RELAXED, __HIP_MEMORY_SCOPE_AGENT);
                if (old == t1 * 64u - 1u) {
                    __hip_atomic_store(gen, t1, __ATOMIC_RELAXED,
                                       __HIP_MEMORY_SCOPE_AGENT);
                } else {
                    while (__hip_atomic_load(gen, __ATOMIC_RELAXED,
                                             __HIP_MEMORY_SCOPE_AGENT) < t1) {
                        __builtin_amdgcn_s_sleep(1);
                    }
                }
            }
            __syncthreads();
        }
    }
}

extern "C" void kernel_launch(void* const* d_in, const int* in_sizes, int n_in,
                              void* d_out, int out_size, void* d_ws, size_t ws_size,
                              hipStream_t stream) {
    const int*   qv   = (const int*)d_in[0];
    const float* Wemb = (const float*)d_in[2];
    const float* Wih  = (const float*)d_in[3];
    const float* Whh  = (const float*)d_in[4];
    const float* b_ih = (const float*)d_in[5];
    const float* b_hh = (const float*)d_in[6];
    float* out = (float*)d_out;

    char* ws = (char*)d_ws;
    size_t off = 0;
    unsigned short* eHi  = (unsigned short*)(ws + off); off += (size_t)MTOT * EMBD * 2;
    unsigned short* ih   = (unsigned short*)(ws + off); off += (size_t)NGATE * EMBD * 2;
    unsigned short* hh   = (unsigned short*)(ws + off); off += (size_t)NGATE * HID * 2;
    unsigned short* hBuf = (unsigned short*)(ws + off); off += (size_t)(SEQW + 1) * NB * HID * 2;
    float* bsum          = (float*)(ws + off);          off += (size_t)NGATE * 4;
    unsigned int* bar    = (unsigned int*)(ws + off);   off += 16384;
    off = (off + 255) & ~(size_t)255;
    float* G0n           = (float*)(ws + off);          off += (size_t)MTOT * NGATE * 4; // 109 MB

    init_kernel<<<NB * HID / 256, 256, 0, stream>>>(hBuf, bar);
    embed_kernel<<<MTOT * EMBD / 256, 256, 0, stream>>>(qv, Wemb, eHi);
    convw_kernel<<<NGATE, 256, 0, stream>>>(Wih, Whh, b_ih, b_hh, ih, hh, bsum);
    pregemm_kernel<<<1664, 512, 0, stream>>>(eHi, ih, bsum, G0n);

    lstm_persist<<<256, 512, 151552, stream>>>(hh, hBuf, G0n, out, bar);
}

// Round 11
// 455.383 us; speedup vs baseline: 1.9826x; 1.4859x over previous
//
#include <hip/hip_runtime.h>
#include <hip/hip_bf16.h>

#define VOCAB 50000
#define EMBD  512
#define HID   1024
#define NB    256
#define SEQW  26
#define MTOT  (SEQW * NB)   /* 6656 */
#define NGATE (4 * HID)     /* 4096 */

typedef short short8 __attribute__((ext_vector_type(8)));
typedef _Float16 half8 __attribute__((ext_vector_type(8)));
typedef float f32x4  __attribute__((ext_vector_type(4)));
typedef float f32x2  __attribute__((ext_vector_type(2)));

__device__ __forceinline__ unsigned short f16bits(_Float16 h) {
    union { _Float16 h; unsigned short u; } cv; cv.h = h; return cv.u;
}

// ---------------- init: zero h slot0 + barrier state ----------------
__global__ void init_kernel(unsigned short* __restrict__ hBuf,
                            unsigned int* __restrict__ bar) {
    int idx = blockIdx.x * blockDim.x + threadIdx.x;  // 1024 x 256
    hBuf[idx] = 0;                                     // slot 0 = h_0 = 0
    if (idx < 4096) bar[idx] = 0;
}

// ---------------- embedding: thread-per-element gather + tanh -> fp16 -------
__global__ void embed_kernel(const int* __restrict__ qv,
                             const float* __restrict__ Wemb,
                             unsigned short* __restrict__ eHi) {
    int gid = blockIdx.x * 256 + threadIdx.x;  // over MTOT*EMBD
    int pair = gid >> 9;                       // t*NB + b
    int e = gid & 511;
    int t = pair >> 8, b = pair & 255;
    int tok = qv[b * SEQW + t];
    unsigned short hi = 0;
    if (tok > 0) {
        float x = Wemb[(size_t)e * VOCAB + (tok - 1)];
        hi = f16bits((_Float16)tanhf(x));
    }
    eHi[gid] = hi;
}

// ---------------- weight conversion: ih fp16, hh fp16, bsum -----------------
__global__ void convw_kernel(const float* __restrict__ Wih,
                             const float* __restrict__ Whh,
                             const float* __restrict__ b_ih,
                             const float* __restrict__ b_hh,
                             unsigned short* __restrict__ ih,
                             unsigned short* __restrict__ hh,
                             float* __restrict__ bsum) {
    int j = blockIdx.x; // 0..4095
    if (threadIdx.x == 0) bsum[j] = b_ih[j] + b_hh[j];
    for (int col = threadIdx.x; col < EMBD; col += blockDim.x)
        ih[(size_t)j * EMBD + col] = f16bits((_Float16)Wih[(size_t)j * EMBD + col]);
    for (int col = threadIdx.x; col < HID; col += blockDim.x)
        hh[(size_t)j * HID + col] = f16bits((_Float16)Whh[(size_t)j * HID + col]);
}

// ---------------- pre-GEMM: G0n = emb @ Wih^T + bias (1-term fp16) ----------
// G0n layout: [t][ct 0..63][b 0..255][cidx 0..63], cidx = gate*16 + (jh&15).
__global__ __launch_bounds__(512, 2) void pregemm_kernel(
    const unsigned short* __restrict__ eHi,
    const unsigned short* __restrict__ ih,
    const float* __restrict__ bsum,
    float* __restrict__ G0n)
{
    int id = blockIdx.x;
    int xcd = id & 7;
    int lid = id >> 3;
    int pc = xcd * 4 + (lid & 3);   // 0..31 col tile (32 jh x 4 gates)
    int pm = lid >> 2;              // 0..51 row tile (128 rows)
    int jh0 = pc * 32;
    int m0  = pm * 128;

    int wave = threadIdx.x >> 6;
    int g  = wave & 3;
    int mh = wave >> 2;
    int lane = threadIdx.x & 63;
    int col16 = lane & 15;
    int g4 = lane >> 4;

    f32x4 acc[4][2];
    #pragma unroll
    for (int fm = 0; fm < 4; ++fm)
        #pragma unroll
        for (int fn = 0; fn < 2; ++fn)
            acc[fm][fn] = (f32x4){0.f, 0.f, 0.f, 0.f};

    const unsigned short* aP[4];
    #pragma unroll
    for (int fm = 0; fm < 4; ++fm)
        aP[fm] = eHi + (size_t)(m0 + mh * 64 + fm * 16 + col16) * EMBD + 8 * g4;
    const unsigned short* bP[2];
    #pragma unroll
    for (int fn = 0; fn < 2; ++fn)
        bP[fn] = ih + (size_t)(g * HID + jh0 + fn * 16 + col16) * EMBD + 8 * g4;

    half8 rA[2][4], rB[2][2];
    #pragma unroll
    for (int fm = 0; fm < 4; ++fm) rA[0][fm] = *(const half8*)(const void*)(aP[fm]);
    #pragma unroll
    for (int fn = 0; fn < 2; ++fn) rB[0][fn] = *(const half8*)(const void*)(bP[fn]);

    #pragma unroll
    for (int kc = 0; kc < 16; ++kc) {
        const int cur = kc & 1, nxt = cur ^ 1;
        if (kc < 15) {
            int off = (kc + 1) * 32;
            #pragma unroll
            for (int fm = 0; fm < 4; ++fm)
                rA[nxt][fm] = *(const half8*)(const void*)(aP[fm] + off);
            #pragma unroll
            for (int fn = 0; fn < 2; ++fn)
                rB[nxt][fn] = *(const half8*)(const void*)(bP[fn] + off);
        }
        #pragma unroll
        for (int fm = 0; fm < 4; ++fm)
            #pragma unroll
            for (int fn = 0; fn < 2; ++fn)
                acc[fm][fn] = __builtin_amdgcn_mfma_f32_16x16x32_f16(
                    rA[cur][fm], rB[cur][fn], acc[fm][fn], 0, 0, 0);
    }

    float bv[2];
    #pragma unroll
    for (int fn = 0; fn < 2; ++fn)
        bv[fn] = bsum[g * HID + jh0 + fn * 16 + col16];

    #pragma unroll
    for (int fm = 0; fm < 4; ++fm)
        #pragma unroll
        for (int fn = 0; fn < 2; ++fn)
            #pragma unroll
            for (int r = 0; r < 4; ++r) {
                int row = m0 + mh * 64 + fm * 16 + g4 * 4 + r;
                int t = row >> 8, b = row & 255;
                int jhc = jh0 + fn * 16 + col16;          // 0..1023
                int ct = jhc >> 4, jl = jhc & 15;
                G0n[(((size_t)t * 64 + ct) * 256 + b) * 64 + g * 16 + jl] =
                    acc[fm][fn][r] + bv[fn];
            }
}

// ---------------- persistent LSTM: B in REGISTERS, A staged in LDS ----------
// 256 blocks x 512 threads (8 waves, 2/SIMD), 1 block/CU.
// Group = 64 blocks (grp=(bx&7)>>1 -> XCD pair): batch rows [grp*64,+64).
// Wave (gate, mh): its 16 Whh gate-rows live in 128 VGPRs/lane (bB[32]),
// loaded ONCE. Per step: h tile (64x1024 fp16 = 128KB, 1x no duplication)
// cooperatively staged into LDS as [kk][g4][row]x16B (conflict-floor for both
// ds_write and A-frag ds_read); K-loop = ds_read A + MFMA only (zero global
// ops, zero vmcnt stalls). h exchange: sc1 relaxed u32 stores; all-relaxed
// flat group barrier (R10-identical).
__global__ __launch_bounds__(512, 2) void lstm_persist(
    const unsigned short* __restrict__ hh,     // fp16 Whh [4096][1024]
    unsigned short* __restrict__ hBuf,         // 27 slots of NB*HID fp16
    const float* __restrict__ G0n,
    float* __restrict__ out,
    unsigned int* __restrict__ bar)
{
    extern __shared__ char smem[];
    // [0,131072): A stage: slab (kk,g4) -> 64 rows x 16B ; addr=((kk*4+g4)*64+row)*16
    // [131072,151552): gbuf[4][64][20] floats
    float* gbuf = (float*)(smem + 131072);

    int bx = blockIdx.x;
    int grp = (bx & 7) >> 1;                     // 0..3
    int ct  = ((bx >> 3) & 31) + 32 * (bx & 1);  // 0..63
    int m0  = grp * 64;
    int jh0 = ct * 16;

    int tid = threadIdx.x;
    int w = tid >> 6;
    int gate = w & 3, mh = w >> 2;
    int lane = tid & 63;
    int col16 = lane & 15, g4 = lane >> 4;

    unsigned int* cnt = bar + grp * 16;
    unsigned int* gen = bar + 1024 + grp * 16;

    // ---- preload B (this wave's 16 Whh gate-rows) into registers ----
    // lane (col16 -> gate-col, g4 -> K-eighth): bB[kk] = halves [kk*32+g4*8, +8)
    half8 bB[32];
    {
        const char* bRow = (const char*)hh +
            ((size_t)(gate * HID + jh0 + col16) * HID + g4 * 8) * 2;
        #pragma unroll
        for (int kk = 0; kk < 32; ++kk)
            bB[kk] = *(const half8*)(const void*)(bRow + kk * 64);
    }

    // epilogue mapping: thread owns (ml = tid>>3, jl2 = 2*(tid&7), +1)
    int ml = tid >> 3, jl2 = (tid & 7) * 2;
    float cReg[2] = {0.f, 0.f};

    for (int t = 0; t < SEQW; ++t) {
        const unsigned short* hIn = hBuf + (size_t)t * NB * HID;
        unsigned short* hOut = hBuf + (size_t)(t + 1) * NB * HID;

        // ---- G0 prefetch for THIS step (hides under staging + K-loop) ----
        f32x2 g0v[4];
        {
            const float* pg = G0n +
                (((size_t)t * 64 + ct) * 256 + (m0 + ml)) * 64 + jl2;
            #pragma unroll
            for (int q = 0; q < 4; ++q) g0v[q] = *(const f32x2*)(pg + q * 16);
        }

        f32x4 acc0 = {0.f, 0.f, 0.f, 0.f};
        f32x4 acc1 = {0.f, 0.f, 0.f, 0.f};

        if (t > 0) {
            // ---- cooperative A stage: wave w handles kk = w*4..w*4+3 ----
            // lane = row; per kk one 64B line per row, 4x16B -> 4 slabs
            {
                const char* hRowB = (const char*)hIn +
                    (size_t)(m0 + lane) * (HID * 2) + w * 256;
                #pragma unroll
                for (int j = 0; j < 4; ++j) {
                    int kk = w * 4 + j;
                    short8 v[4];
                    #pragma unroll
                    for (int q = 0; q < 4; ++q)
                        v[q] = *(const short8*)(const void*)(hRowB + j * 64 + q * 16);
                    #pragma unroll
                    for (int q = 0; q < 4; ++q)
                        *(short8*)(smem + ((kk * 4 + q) * 64 + lane) * 16) = v[q];
                }
            }
            __syncthreads();

            // ---- K loop: A from LDS, B from registers, zero global ops ----
            #pragma unroll
            for (int kk = 0; kk < 32; ++kk) {
                const char* slab = smem + (kk * 4 + g4) * 1024;
                half8 a0 = *(const half8*)(const void*)(slab + (mh * 32 + col16) * 16);
                half8 a1 = *(const half8*)(const void*)(slab + (mh * 32 + 16 + col16) * 16);
                acc0 = __builtin_amdgcn_mfma_f32_16x16x32_f16(a0, bB[kk], acc0, 0, 0, 0);
                acc1 = __builtin_amdgcn_mfma_f32_16x16x32_f16(a1, bB[kk], acc1, 0, 0, 0);
            }
        }

        // scatter: gbuf[gate][row][col16], row stride 20 floats
        #pragma unroll
        for (int r = 0; r < 4; ++r) {
            gbuf[(gate * 64 + mh * 32 + g4 * 4 + r) * 20 + col16] = acc0[r];
            gbuf[(gate * 64 + mh * 32 + 16 + g4 * 4 + r) * 20 + col16] = acc1[r];
        }
        __syncthreads();

        // ---- epilogue: 2 adjacent cells/thread, c in registers ----
        f32x2 gv[4];
        #pragma unroll
        for (int q = 0; q < 4; ++q)
            gv[q] = *(const f32x2*)&gbuf[(q * 64 + ml) * 20 + jl2];

        float hN[2];
        #pragma unroll
        for (int u = 0; u < 2; ++u) {
            float gi  = gv[0][u] + g0v[0][u];
            float gf  = gv[1][u] + g0v[1][u];
            float gg_ = gv[2][u] + g0v[2][u];
            float go  = gv[3][u] + g0v[3][u];
            float si = 1.0f / (1.0f + expf(-gi));
            float sf = 1.0f / (1.0f + expf(-gf));
            float so = 1.0f / (1.0f + expf(-go));
            float tg = tanhf(gg_);
            float cN = sf * cReg[u] + si * tg;
            hN[u] = so * tanhf(cN);
            cReg[u] = cN;
        }
        size_t p = (size_t)(m0 + ml) * HID + jh0 + jl2;
        if (t == SEQW - 1) {
            *(f32x2*)(out + p) = (f32x2){hN[0], hN[1]};
        } else {
            unsigned int hv = (unsigned int)f16bits((_Float16)hN[0]) |
                              ((unsigned int)f16bits((_Float16)hN[1]) << 16);
            __hip_atomic_store((unsigned int*)(hOut + p), hv,
                               __ATOMIC_RELAXED, __HIP_MEMORY_SCOPE_AGENT);

            // ---- group barrier: all-relaxed (sc1 data already at L3) ----
            __syncthreads();   // drains vmcnt: h stores acked at L3
            if (tid == 0) {
                unsigned int t1 = (unsigned int)(t + 1);
                unsigned int old = __hip_atomic_fetch_add(
                    cnt, 1u, __ATOMIC_RELAXED, __HIP_MEMORY_SCOPE_AGENT);
                if (old == t1 * 64u - 1u) {
                    __hip_atomic_store(gen, t1, __ATOMIC_RELAXED,
                                       __HIP_MEMORY_SCOPE_AGENT);
                } else {
                    while (__hip_atomic_load(gen, __ATOMIC_RELAXED,
                                             __HIP_MEMORY_SCOPE_AGENT) < t1) {
                        __builtin_amdgcn_s_sleep(1);
                    }
                }
            }
            __syncthreads();
        }
    }
}

extern "C" void kernel_launch(void* const* d_in, const int* in_sizes, int n_in,
                              void* d_out, int out_size, void* d_ws, size_t ws_size,
                              hipStream_t stream) {
    const int*   qv   = (const int*)d_in[0];
    const float* Wemb = (const float*)d_in[2];
    const float* Wih  = (const float*)d_in[3];
    const float* Whh  = (const float*)d_in[4];
    const float* b_ih = (const float*)d_in[5];
    const float* b_hh = (const float*)d_in[6];
    float* out = (float*)d_out;

    char* ws = (char*)d_ws;
    size_t off = 0;
    unsigned short* eHi  = (unsigned short*)(ws + off); off += (size_t)MTOT * EMBD * 2;
    unsigned short* ih   = (unsigned short*)(ws + off); off += (size_t)NGATE * EMBD * 2;
    unsigned short* hh   = (unsigned short*)(ws + off); off += (size_t)NGATE * HID * 2;
    unsigned short* hBuf = (unsigned short*)(ws + off); off += (size_t)(SEQW + 1) * NB * HID * 2;
    float* bsum          = (float*)(ws + off);          off += (size_t)NGATE * 4;
    unsigned int* bar    = (unsigned int*)(ws + off);   off += 16384;
    off = (off + 255) & ~(size_t)255;
    float* G0n           = (float*)(ws + off);          off += (size_t)MTOT * NGATE * 4; // 109 MB

    init_kernel<<<NB * HID / 256, 256, 0, stream>>>(hBuf, bar);
    embed_kernel<<<MTOT * EMBD / 256, 256, 0, stream>>>(qv, Wemb, eHi);
    convw_kernel<<<NGATE, 256, 0, stream>>>(Wih, Whh, b_ih, b_hh, ih, hh, bsum);
    pregemm_kernel<<<1664, 512, 0, stream>>>(eHi, ih, bsum, G0n);

    lstm_persist<<<256, 512, 151552, stream>>>(hh, hBuf, G0n, out, bar);
}

// Round 12
// 294.598 us; speedup vs baseline: 3.0647x; 1.5458x over previous
//
#include <hip/hip_runtime.h>
#include <hip/hip_bf16.h>

#define VOCAB 50000
#define EMBD  512
#define HID   1024
#define NB    256
#define SEQW  26
#define MTOT  (SEQW * NB)   /* 6656 */
#define NGATE (4 * HID)     /* 4096 */

typedef short short8 __attribute__((ext_vector_type(8)));
typedef _Float16 half8 __attribute__((ext_vector_type(8)));
typedef float f32x4  __attribute__((ext_vector_type(4)));
typedef float f32x2  __attribute__((ext_vector_type(2)));

__device__ __forceinline__ unsigned short f16bits(_Float16 h) {
    union { _Float16 h; unsigned short u; } cv; cv.h = h; return cv.u;
}

__device__ __forceinline__ void gload16(const void* g, void* l) {
    __builtin_amdgcn_global_load_lds(
        (const __attribute__((address_space(1))) void*)g,
        (__attribute__((address_space(3))) void*)l, 16, 0, 0);
}

// ---------------- init: zero h slot0 + barrier state ----------------
__global__ void init_kernel(unsigned short* __restrict__ hBuf,
                            unsigned int* __restrict__ bar) {
    int idx = blockIdx.x * blockDim.x + threadIdx.x;  // 1024 x 256
    hBuf[idx] = 0;                                     // slot 0 = h_0 = 0
    if (idx < 4096) bar[idx] = 0;
}

// ---------------- Wemb transpose: [512][50000] f32 -> WembT [50000][512] f16
// grid (782, 8), 256 thr. LDS tile 64v x 64e. Both sides coalesced.
__global__ void transp_kernel(const float* __restrict__ W,
                              unsigned short* __restrict__ WT) {
    __shared__ _Float16 tile[64][72];
    int v0 = blockIdx.x * 64;
    int e0 = blockIdx.y * 64;
    int tid = threadIdx.x;

    // read: thread (e_loc = tid>>2, q = tid&3): 64B contiguous (4x f32x4)
    int e_loc = tid >> 2, q = tid & 3;
    int vq = q * 16;
    if (v0 + vq < VOCAB) {   // 16-chunks are exactly in/out (VOCAB%16==0)
        const float* src = W + (size_t)(e0 + e_loc) * VOCAB + v0 + vq;
        #pragma unroll
        for (int j = 0; j < 4; ++j) {
            f32x4 x = *(const f32x4*)(src + 4 * j);
            #pragma unroll
            for (int i = 0; i < 4; ++i)
                tile[vq + 4 * j + i][e_loc] = (_Float16)x[i];
        }
    }
    __syncthreads();

    // write: thread (v_loc = tid>>2, q): 32B contiguous per thread
    int v_loc = tid >> 2;
    int ec = q * 16;
    int v = v0 + v_loc;
    if (v < VOCAB) {
        short8* dst = (short8*)(WT + (size_t)v * EMBD + e0 + ec);
        dst[0] = *(const short8*)&tile[v_loc][ec];
        dst[1] = *(const short8*)&tile[v_loc][ec + 8];
    }
}

// ---------------- embedding: row-gather from WembT + tanh -> fp16 -----------
// 1664 blocks x 256 thr (4 waves); wave handles one (t,b) pair: 64 lanes x 16B.
__global__ void embed_kernel(const int* __restrict__ qv,
                             const unsigned short* __restrict__ WT,
                             unsigned short* __restrict__ eHi) {
    int pair = blockIdx.x * 4 + (threadIdx.x >> 6);
    int t = pair >> 8, b = pair & 255;
    int lane = threadIdx.x & 63;
    int tok = qv[b * SEQW + t];
    short8 out = {};
    if (tok > 0) {
        short8 v = *(const short8*)(WT + (size_t)(tok - 1) * EMBD + lane * 8);
        #pragma unroll
        for (int i = 0; i < 8; ++i) {
            union { short s; _Float16 h; } cv; cv.s = v[i];
            out[i] = (short)f16bits((_Float16)tanhf((float)cv.h));
        }
    }
    *(short8*)(eHi + (size_t)pair * EMBD + lane * 8) = out;
}

// ---------------- weight conversion: ih fp16, hh fp16, bsum -----------------
__global__ void convw_kernel(const float* __restrict__ Wih,
                             const float* __restrict__ Whh,
                             const float* __restrict__ b_ih,
                             const float* __restrict__ b_hh,
                             unsigned short* __restrict__ ih,
                             unsigned short* __restrict__ hh,
                             float* __restrict__ bsum) {
    int j = blockIdx.x; // 0..4095
    if (threadIdx.x == 0) bsum[j] = b_ih[j] + b_hh[j];
    for (int col = threadIdx.x; col < EMBD; col += blockDim.x)
        ih[(size_t)j * EMBD + col] = f16bits((_Float16)Wih[(size_t)j * EMBD + col]);
    for (int col = threadIdx.x; col < HID; col += blockDim.x)
        hh[(size_t)j * HID + col] = f16bits((_Float16)Whh[(size_t)j * HID + col]);
}

// ---------------- pre-GEMM v2: LDS-staged (m97-style), fp16 1-term ----------
// Tile 128(M) x 128 gate-cols, BK=64, dbuf LDS 64KB, 8 waves (mh x nh 2x4),
// wave = 4x2 16x16x32 frags. Stage via global_load_lds w16: linear LDS dest,
// XOR-swizzled SOURCE chunk (G21); frag ds_read uses same XOR -> 2-way free.
// Tile col c' = gate(2b)|jh_low(5b); B global row = gate*1024 + pc*32 + jh_low.
__global__ __launch_bounds__(512, 2) void pregemm_kernel(
    const unsigned short* __restrict__ eHi,
    const unsigned short* __restrict__ ih,
    const float* __restrict__ bsum,
    float* __restrict__ G0n)
{
    __shared__ char smem[65536];   // A dbuf [2][16KB] @0, B dbuf [2][16KB] @32768

    int id = blockIdx.x;
    int xcd = id & 7, lid = id >> 3;
    int pc = xcd * 4 + (lid & 3);   // 0..31
    int pm = lid >> 2;              // 0..51
    int m0 = pm * 128;

    int tid = threadIdx.x;
    int w = tid >> 6;               // 0..7
    int mh = w >> 2, nh = w & 3;
    int lane = tid & 63;
    int col16 = lane & 15, g4 = lane >> 4;

    // staging: wave w covers rows [w*16, +16) in 2 ops of 8 rows
    int sr = lane >> 3, sc = lane & 7;
    int ra0 = w * 16 + sr, ra1 = ra0 + 8;
    const char* eB = (const char*)eHi;
    const char* iB = (const char*)ih;
    size_t aOffG0 = (size_t)(m0 + ra0) * 1024 + (size_t)(((sc ^ (ra0 & 7))) * 16);
    size_t aOffG1 = (size_t)(m0 + ra1) * 1024 + (size_t)(((sc ^ (ra1 & 7))) * 16);
    int gb0 = (ra0 >> 5) * 1024 + pc * 32 + (ra0 & 31);
    int gb1 = (ra1 >> 5) * 1024 + pc * 32 + (ra1 & 31);
    size_t bOffG0 = (size_t)gb0 * 1024 + (size_t)(((sc ^ (ra0 & 7))) * 16);
    size_t bOffG1 = (size_t)gb1 * 1024 + (size_t)(((sc ^ (ra1 & 7))) * 16);
    int ldsRow0 = (w * 16) * 128;        // wave-uniform bases
    int ldsRow1 = (w * 16 + 8) * 128;

    f32x4 acc[4][2];
    #pragma unroll
    for (int fm = 0; fm < 4; ++fm)
        #pragma unroll
        for (int fn = 0; fn < 2; ++fn)
            acc[fm][fn] = (f32x4){0.f, 0.f, 0.f, 0.f};

    // frag read row offsets (XOR swizzle key = col16&7, same rows for A/B)
    int swb = col16 & 7;
    int aRow[4], bRow[2];
    #pragma unroll
    for (int fm = 0; fm < 4; ++fm) aRow[fm] = (mh * 64 + fm * 16 + col16) * 128;
    #pragma unroll
    for (int fn = 0; fn < 2; ++fn) bRow[fn] = (nh * 32 + fn * 16 + col16) * 128;

#define STAGE(kb, buf) do { \
        int kby = (kb) * 128; \
        char* aD = smem + (buf) * 16384; \
        char* bD = smem + 32768 + (buf) * 16384; \
        gload16(eB + aOffG0 + kby, aD + ldsRow0); \
        gload16(eB + aOffG1 + kby, aD + ldsRow1); \
        gload16(iB + bOffG0 + kby, bD + ldsRow0); \
        gload16(iB + bOffG1 + kby, bD + ldsRow1); \
    } while (0)

    STAGE(0, 0);
    #pragma unroll
    for (int kb = 0; kb < 8; ++kb) {
        int cur = kb & 1;
        __syncthreads();                 // drains stage(kb); prev compute done
        if (kb < 7) STAGE(kb + 1, cur ^ 1);
        const char* aS = smem + cur * 16384;
        const char* bS = smem + 32768 + cur * 16384;
        #pragma unroll
        for (int kk = 0; kk < 2; ++kk) {
            int co = ((kk * 4 + g4) ^ swb) * 16;
            half8 bF[2];
            #pragma unroll
            for (int fn = 0; fn < 2; ++fn)
                bF[fn] = *(const half8*)(const void*)(bS + bRow[fn] + co);
            #pragma unroll
            for (int fm = 0; fm < 4; ++fm) {
                half8 aF = *(const half8*)(const void*)(aS + aRow[fm] + co);
                #pragma unroll
                for (int fn = 0; fn < 2; ++fn)
                    acc[fm][fn] = __builtin_amdgcn_mfma_f32_16x16x32_f16(
                        aF, bF[fn], acc[fm][fn], 0, 0, 0);
            }
        }
    }
#undef STAGE

    // epilogue: scattered fp32 writes to G0n[t][ct][b][cidx] + bias
    #pragma unroll
    for (int fn = 0; fn < 2; ++fn) {
        int cp = nh * 32 + fn * 16 + col16;   // tile col 0..127
        int gate = cp >> 5;
        int jh = pc * 32 + (cp & 31);
        int ct = jh >> 4, jl = jh & 15;
        int cidx = gate * 16 + jl;
        float bv = bsum[gate * HID + jh];
        #pragma unroll
        for (int fm = 0; fm < 4; ++fm)
            #pragma unroll
            for (int r = 0; r < 4; ++r) {
                int row = m0 + mh * 64 + fm * 16 + g4 * 4 + r;
                int t = row >> 8, b = row & 255;
                G0n[(((size_t)t * 64 + ct) * 256 + b) * 64 + cidx] =
                    acc[fm][fn][r] + bv;
            }
    }
}

// ---------------- persistent LSTM: B in REGISTERS, A staged in LDS ----------
// (unchanged from R11: 224 us, 8.6 us/step)
__global__ __launch_bounds__(512, 2) void lstm_persist(
    const unsigned short* __restrict__ hh,     // fp16 Whh [4096][1024]
    unsigned short* __restrict__ hBuf,         // 27 slots of NB*HID fp16
    const float* __restrict__ G0n,
    float* __restrict__ out,
    unsigned int* __restrict__ bar)
{
    extern __shared__ char smem[];
    float* gbuf = (float*)(smem + 131072);

    int bx = blockIdx.x;
    int grp = (bx & 7) >> 1;                     // 0..3
    int ct  = ((bx >> 3) & 31) + 32 * (bx & 1);  // 0..63
    int m0  = grp * 64;
    int jh0 = ct * 16;

    int tid = threadIdx.x;
    int w = tid >> 6;
    int gate = w & 3, mh = w >> 2;
    int lane = tid & 63;
    int col16 = lane & 15, g4 = lane >> 4;

    unsigned int* cnt = bar + grp * 16;
    unsigned int* gen = bar + 1024 + grp * 16;

    // ---- preload B (this wave's 16 Whh gate-rows) into registers ----
    half8 bB[32];
    {
        const char* bRow = (const char*)hh +
            ((size_t)(gate * HID + jh0 + col16) * HID + g4 * 8) * 2;
        #pragma unroll
        for (int kk = 0; kk < 32; ++kk)
            bB[kk] = *(const half8*)(const void*)(bRow + kk * 64);
    }

    int ml = tid >> 3, jl2 = (tid & 7) * 2;
    float cReg[2] = {0.f, 0.f};

    for (int t = 0; t < SEQW; ++t) {
        const unsigned short* hIn = hBuf + (size_t)t * NB * HID;
        unsigned short* hOut = hBuf + (size_t)(t + 1) * NB * HID;

        f32x2 g0v[4];
        {
            const float* pg = G0n +
                (((size_t)t * 64 + ct) * 256 + (m0 + ml)) * 64 + jl2;
            #pragma unroll
            for (int q = 0; q < 4; ++q) g0v[q] = *(const f32x2*)(pg + q * 16);
        }

        f32x4 acc0 = {0.f, 0.f, 0.f, 0.f};
        f32x4 acc1 = {0.f, 0.f, 0.f, 0.f};

        if (t > 0) {
            {
                const char* hRowB = (const char*)hIn +
                    (size_t)(m0 + lane) * (HID * 2) + w * 256;
                #pragma unroll
                for (int j = 0; j < 4; ++j) {
                    int kk = w * 4 + j;
                    short8 v[4];
                    #pragma unroll
                    for (int q = 0; q < 4; ++q)
                        v[q] = *(const short8*)(const void*)(hRowB + j * 64 + q * 16);
                    #pragma unroll
                    for (int q = 0; q < 4; ++q)
                        *(short8*)(smem + ((kk * 4 + q) * 64 + lane) * 16) = v[q];
                }
            }
            __syncthreads();

            #pragma unroll
            for (int kk = 0; kk < 32; ++kk) {
                const char* slab = smem + (kk * 4 + g4) * 1024;
                half8 a0 = *(const half8*)(const void*)(slab + (mh * 32 + col16) * 16);
                half8 a1 = *(const half8*)(const void*)(slab + (mh * 32 + 16 + col16) * 16);
                acc0 = __builtin_amdgcn_mfma_f32_16x16x32_f16(a0, bB[kk], acc0, 0, 0, 0);
                acc1 = __builtin_amdgcn_mfma_f32_16x16x32_f16(a1, bB[kk], acc1, 0, 0, 0);
            }
        }

        #pragma unroll
        for (int r = 0; r < 4; ++r) {
            gbuf[(gate * 64 + mh * 32 + g4 * 4 + r) * 20 + col16] = acc0[r];
            gbuf[(gate * 64 + mh * 32 + 16 + g4 * 4 + r) * 20 + col16] = acc1[r];
        }
        __syncthreads();

        f32x2 gv[4];
        #pragma unroll
        for (int q = 0; q < 4; ++q)
            gv[q] = *(const f32x2*)&gbuf[(q * 64 + ml) * 20 + jl2];

        float hN[2];
        #pragma unroll
        for (int u = 0; u < 2; ++u) {
            float gi  = gv[0][u] + g0v[0][u];
            float gf  = gv[1][u] + g0v[1][u];
            float gg_ = gv[2][u] + g0v[2][u];
            float go  = gv[3][u] + g0v[3][u];
            float si = 1.0f / (1.0f + expf(-gi));
            float sf = 1.0f / (1.0f + expf(-gf));
            float so = 1.0f / (1.0f + expf(-go));
            float tg = tanhf(gg_);
            float cN = sf * cReg[u] + si * tg;
            hN[u] = so * tanhf(cN);
            cReg[u] = cN;
        }
        size_t p = (size_t)(m0 + ml) * HID + jh0 + jl2;
        if (t == SEQW - 1) {
            *(f32x2*)(out + p) = (f32x2){hN[0], hN[1]};
        } else {
            unsigned int hv = (unsigned int)f16bits((_Float16)hN[0]) |
                              ((unsigned int)f16bits((_Float16)hN[1]) << 16);
            __hip_atomic_store((unsigned int*)(hOut + p), hv,
                               __ATOMIC_RELAXED, __HIP_MEMORY_SCOPE_AGENT);

            __syncthreads();
            if (tid == 0) {
                unsigned int t1 = (unsigned int)(t + 1);
                unsigned int old = __hip_atomic_fetch_add(
                    cnt, 1u, __ATOMIC_RELAXED, __HIP_MEMORY_SCOPE_AGENT);
                if (old == t1 * 64u - 1u) {
                    __hip_atomic_store(gen, t1, __ATOMIC_RELAXED,
                                       __HIP_MEMORY_SCOPE_AGENT);
                } else {
                    while (__hip_atomic_load(gen, __ATOMIC_RELAXED,
                                             __HIP_MEMORY_SCOPE_AGENT) < t1) {
                        __builtin_amdgcn_s_sleep(1);
                    }
                }
            }
            __syncthreads();
        }
    }
}

extern "C" void kernel_launch(void* const* d_in, const int* in_sizes, int n_in,
                              void* d_out, int out_size, void* d_ws, size_t ws_size,
                              hipStream_t stream) {
    const int*   qv   = (const int*)d_in[0];
    const float* Wemb = (const float*)d_in[2];
    const float* Wih  = (const float*)d_in[3];
    const float* Whh  = (const float*)d_in[4];
    const float* b_ih = (const float*)d_in[5];
    const float* b_hh = (const float*)d_in[6];
    float* out = (float*)d_out;

    char* ws = (char*)d_ws;
    size_t off = 0;
    unsigned short* eHi  = (unsigned short*)(ws + off); off += (size_t)MTOT * EMBD * 2;
    unsigned short* ih   = (unsigned short*)(ws + off); off += (size_t)NGATE * EMBD * 2;
    unsigned short* hh   = (unsigned short*)(ws + off); off += (size_t)NGATE * HID * 2;
    unsigned short* hBuf = (unsigned short*)(ws + off); off += (size_t)(SEQW + 1) * NB * HID * 2;
    float* bsum          = (float*)(ws + off);          off += (size_t)NGATE * 4;
    unsigned int* bar    = (unsigned int*)(ws + off);   off += 16384;
    off = (off + 255) & ~(size_t)255;
    float* G0n           = (float*)(ws + off);          off += (size_t)MTOT * NGATE * 4; // 109 MB
    // WembT aliases the G0n region: dead before pregemm writes G0n
    unsigned short* WembT = (unsigned short*)G0n;       // 51.2 MB < 109 MB

    init_kernel<<<NB * HID / 256, 256, 0, stream>>>(hBuf, bar);
    transp_kernel<<<dim3(782, 8), 256, 0, stream>>>(Wemb, WembT);
    embed_kernel<<<MTOT / 4, 256, 0, stream>>>(qv, WembT, eHi);
    convw_kernel<<<NGATE, 256, 0, stream>>>(Wih, Whh, b_ih, b_hh, ih, hh, bsum);
    pregemm_kernel<<<1664, 512, 0, stream>>>(eHi, ih, bsum, G0n);

    lstm_persist<<<256, 512, 151552, stream>>>(hh, hBuf, G0n, out, bar);
}